// Round 16
// baseline (349.588 us; speedup 1.0000x reference)
//
#include <hip/hip_runtime.h>

#define NH 12
#define HD 32
#define DIMC 384
#define BATCH 32
#define HWIMG 56
#define NWIN 2048          // 32 batches * 64 windows
#define NROWS 100352       // NWIN * 49, dense window-gathered rows
#define QKV_M 1152
#define KDIM 384
#define QSCALE 0.17677669529663687f

typedef __attribute__((ext_vector_type(8))) short short8;
typedef __attribute__((ext_vector_type(4))) short short4v;
typedef __attribute__((ext_vector_type(4))) float f32x4;

typedef const __attribute__((address_space(1))) unsigned int* gas_ptr;
typedef __attribute__((address_space(3))) unsigned int* las_ptr;

__device__ __forceinline__ unsigned short f2bf(float f) {
    union { float f; unsigned u; } v; v.f = f;
    unsigned r = v.u + 0x7FFF + ((v.u >> 16) & 1);
    return (unsigned short)(r >> 16);
}

// ---------------- fp32 -> bf16 weight convert; first scale_elems get * QSCALE --------
__global__ __launch_bounds__(256) void cvt_w(const float* __restrict__ in,
                                             unsigned short* __restrict__ out,
                                             int n, int scale_elems) {
    int i = blockIdx.x * 256 + threadIdx.x;
    if (i < n) {
        float v = in[i];
        if (i < scale_elems) v *= QSCALE;
        out[i] = f2bf(v);
    }
}

// ---------------- x [B,384,56,56] fp32 -> xt [NROWS,384] bf16 (R13-proven) ----------
__global__ __launch_bounds__(256) void cvt_x(const float* __restrict__ x,
                                             unsigned short* __restrict__ xt) {
    __shared__ float tile[32][33];
    const int b = blockIdx.z, c0 = blockIdx.y * 32, n0 = blockIdx.x * 32;
    const int tid = threadIdx.x;
    const int cl = tid >> 5, nl = tid & 31;
    #pragma unroll
    for (int p = 0; p < 4; ++p)
        tile[cl + p * 8][nl] = x[((size_t)b * DIMC + c0 + cl + p * 8) * 3136 + n0 + nl];
    __syncthreads();
    const int nl2 = tid >> 3, cq = (tid & 7) * 4;
    const int n = n0 + nl2;
    const int nh = n / HWIMG, nw = n % HWIMG;
    const int row = ((b * 64 + (nh / 7) * 8 + nw / 7) * 49 + (nh % 7) * 7 + nw % 7);
    short4v pk;
    #pragma unroll
    for (int u = 0; u < 4; ++u) pk[u] = (short)f2bf(tile[cq + u][nl2]);
    *(short4v*)(xt + (size_t)row * KDIM + c0 + cq) = pk;
}

// ---------------- bias expand: biasp[h][j:64][i:64] fp32, transposed & padded ----------
__global__ __launch_bounds__(256) void fill_bias(const float* __restrict__ bias_table,
                                                 const int* __restrict__ rel_index,
                                                 float* __restrict__ biasp) {
    int id = blockIdx.x * 256 + threadIdx.x;   // 12*4096
    int h = id >> 12, r = id & 4095;
    int j = r >> 6, i = r & 63;
    float v = 0.f;
    if (i < 49 && j < 49) v = bias_table[rel_index[i * 49 + j] * NH + h];
    biasp[id] = v;
}

// ============ GEMM1 (R13-proven): 2-phase 128x128 K-loop + coalesced LDS epilogue =====
__global__ __launch_bounds__(256) void gemm_qkv(
    const unsigned short* __restrict__ A,     // wqb [1152][384] (q rows pre-scaled)
    const unsigned short* __restrict__ Bm,    // xt [NROWS][384]
    unsigned short* __restrict__ qk)          // qkw2 [NROWS][1152]
{
    __shared__ char LBUF[32768];              // K-loop: A|B 16KB each; epilogue: C tile
    char* Al = LBUF;
    char* Bl = LBUF + 16384;
    const int tid = threadIdx.x;

    constexpr int MT = 9;
    const unsigned nwg = gridDim.x;
    const unsigned lin = blockIdx.x;
    const unsigned swz = (lin & 7) * (nwg >> 3) + (lin >> 3);  // XCD-contiguous
    const int m0 = (int)(swz % MT) * 128;
    const int ng0 = (int)(swz / MT) * 128;

    const int lane = tid & 63;
    const int wv = tid >> 6;
    const int wr = wv >> 1, wc = wv & 1;
    const int lrow = lane & 15, kgrp = lane >> 4;

    f32x4 acc[4][4] = {};

    const char* Abase = (const char*)(A + (size_t)m0 * KDIM);
    const char* Bbase = (const char*)(Bm + (size_t)ng0 * KDIM);

    for (int kt = 0; kt < KDIM / 64; ++kt) {
        const int kb = kt * 128;
        #pragma unroll
        for (int it = 0; it < 4; ++it) {
            int chunk = it * 256 + tid;
            int row = chunk >> 3, slot = chunk & 7;
            int scol = (slot ^ (row & 7)) * 16;
            __builtin_amdgcn_global_load_lds(
                (gas_ptr)(Abase + (size_t)row * (KDIM * 2) + kb + scol),
                (las_ptr)(Al + chunk * 16), 16, 0, 0);
        }
        #pragma unroll
        for (int it = 0; it < 4; ++it) {
            int chunk = it * 256 + tid;
            int row = chunk >> 3, slot = chunk & 7;
            int scol = (slot ^ (row & 7)) * 16;
            __builtin_amdgcn_global_load_lds(
                (gas_ptr)(Bbase + (size_t)row * (KDIM * 2) + kb + scol),
                (las_ptr)(Bl + chunk * 16), 16, 0, 0);
        }
        __syncthreads();
        #pragma unroll
        for (int kk = 0; kk < 2; ++kk) {
            short8 af[4], bfr[4];
            #pragma unroll
            for (int i = 0; i < 4; ++i) {
                int row = wr * 64 + i * 16 + lrow;
                int slot = (kk * 4 + kgrp) ^ (row & 7);
                af[i] = *(const short8*)(Al + row * 128 + slot * 16);
            }
            #pragma unroll
            for (int j = 0; j < 4; ++j) {
                int row = wc * 64 + j * 16 + lrow;
                int slot = (kk * 4 + kgrp) ^ (row & 7);
                bfr[j] = *(const short8*)(Bl + row * 128 + slot * 16);
            }
            __builtin_amdgcn_s_setprio(1);
            #pragma unroll
            for (int i = 0; i < 4; ++i)
                #pragma unroll
                for (int j = 0; j < 4; ++j)
                    acc[i][j] = __builtin_amdgcn_mfma_f32_16x16x32_bf16(af[i], bfr[j], acc[i][j], 0, 0, 0);
            __builtin_amdgcn_s_setprio(0);
        }
        __syncthreads();   // all LDS reads done -> safe to repurpose LBUF after loop
    }

    // ---- epilogue: C -> LDS [128 ng][256 B m-slice], XOR-swizzled 16B chunks ----
    #pragma unroll
    for (int i = 0; i < 4; ++i) {
        int mpl = wr * 64 + i * 16 + kgrp * 4;     // local m (covers 4)
        #pragma unroll
        for (int j = 0; j < 4; ++j) {
            int ngl = wc * 64 + j * 16 + lrow;     // local ng
            short4v pk;
            pk.x = (short)f2bf(acc[i][j].x);
            pk.y = (short)f2bf(acc[i][j].y);
            pk.z = (short)f2bf(acc[i][j].z);
            pk.w = (short)f2bf(acc[i][j].w);
            *(short4v*)(LBUF + ngl * 256 + ((mpl * 2) ^ ((ngl & 7) << 4))) = pk;
        }
    }
    __syncthreads();
    // ---- coalesced store: 2048 16-B chunks, 8 per thread ----
    #pragma unroll
    for (int p = 0; p < 8; ++p) {
        int ch = p * 256 + tid;
        int ngl = ch >> 4, q = ch & 15;
        short8 v = *(const short8*)(LBUF + ngl * 256 + ((q * 16) ^ ((ngl & 7) << 4)));
        *(short8*)(qk + (size_t)(ng0 + ngl) * QKV_M + m0 + q * 8) = v;
    }
}

// ---------------- proj GEMM (R4-proven): C = w_proj @ att^T + bias, fp32 NCHW -------
__global__ __launch_bounds__(256) void gemm_proj(
    const unsigned short* __restrict__ A,     // [384][384] bf16
    const unsigned short* __restrict__ Bm,    // att [NROWS][384] spatial-major
    const float* __restrict__ bias,
    float* __restrict__ C)
{
    __shared__ char Al[128 * 128];
    __shared__ char Bl[128 * 128];
    const int tid = threadIdx.x;

    constexpr int MT = 3;
    const unsigned nwg = gridDim.x;
    const unsigned lin = blockIdx.x;
    const unsigned swz = (lin & 7) * (nwg >> 3) + (lin >> 3);
    const int m0 = (int)(swz % MT) * 128;
    const int ng0 = (int)(swz / MT) * 128;

    const int lane = tid & 63;
    const int wv = tid >> 6;
    const int wr = wv >> 1, wc = wv & 1;
    const int lrow = lane & 15, kgrp = lane >> 4;

    f32x4 acc[4][4] = {};

    const char* Abase = (const char*)(A + (size_t)m0 * KDIM);
    const char* Bbase = (const char*)(Bm + (size_t)ng0 * KDIM);

    for (int kt = 0; kt < KDIM / 64; ++kt) {
        const int kb = kt * 128;
        #pragma unroll
        for (int it = 0; it < 4; ++it) {
            int chunk = it * 256 + tid;
            int row = chunk >> 3, slot = chunk & 7;
            int scol = (slot ^ (row & 7)) * 16;
            __builtin_amdgcn_global_load_lds(
                (gas_ptr)(Abase + (size_t)row * (KDIM * 2) + kb + scol),
                (las_ptr)(Al + chunk * 16), 16, 0, 0);
        }
        #pragma unroll
        for (int it = 0; it < 4; ++it) {
            int chunk = it * 256 + tid;
            int row = chunk >> 3, slot = chunk & 7;
            int scol = (slot ^ (row & 7)) * 16;
            __builtin_amdgcn_global_load_lds(
                (gas_ptr)(Bbase + (size_t)row * (KDIM * 2) + kb + scol),
                (las_ptr)(Bl + chunk * 16), 16, 0, 0);
        }
        __syncthreads();
        #pragma unroll
        for (int kk = 0; kk < 2; ++kk) {
            short8 af[4], bfr[4];
            #pragma unroll
            for (int i = 0; i < 4; ++i) {
                int row = wr * 64 + i * 16 + lrow;
                int slot = (kk * 4 + kgrp) ^ (row & 7);
                af[i] = *(const short8*)(Al + row * 128 + slot * 16);
            }
            #pragma unroll
            for (int j = 0; j < 4; ++j) {
                int row = wc * 64 + j * 16 + lrow;
                int slot = (kk * 4 + kgrp) ^ (row & 7);
                bfr[j] = *(const short8*)(Bl + row * 128 + slot * 16);
            }
            __builtin_amdgcn_s_setprio(1);
            #pragma unroll
            for (int i = 0; i < 4; ++i)
                #pragma unroll
                for (int j = 0; j < 4; ++j)
                    acc[i][j] = __builtin_amdgcn_mfma_f32_16x16x32_bf16(af[i], bfr[j], acc[i][j], 0, 0, 0);
            __builtin_amdgcn_s_setprio(0);
        }
        __syncthreads();
    }

    #pragma unroll
    for (int i = 0; i < 4; ++i) {
        int m = m0 + wr * 64 + i * 16 + kgrp * 4;
        float b0 = bias[m + 0], b1 = bias[m + 1], b2 = bias[m + 2], b3 = bias[m + 3];
        #pragma unroll
        for (int j = 0; j < 4; ++j) {
            int ng = ng0 + wc * 64 + j * 16 + lrow;
            unsigned bb = (unsigned)ng / 3136u;
            unsigned nsp = (unsigned)ng - bb * 3136u;
            C[((size_t)bb * DIMC + m + 0) * 3136 + nsp] = acc[i][j].x + b0;
            C[((size_t)bb * DIMC + m + 1) * 3136 + nsp] = acc[i][j].y + b1;
            C[((size_t)bb * DIMC + m + 2) * 3136 + nsp] = acc[i][j].z + b2;
            C[((size_t)bb * DIMC + m + 3) * 3136 + nsp] = acc[i][j].w + b3;
        }
    }
}

// ---------------- MFMA windowed attention: block = 1 window x 12 heads (768 thr) -----
// All reads of a window's qkw2 rows stay in ONE block (one XCD L2 fetch per line);
// O bounced through LDS -> full 768-B contiguous row stores.
__global__ __launch_bounds__(768) void win_attn(
    const unsigned short* __restrict__ qkw,   // [NROWS][1152], q pre-scaled
    const float* __restrict__ biasp,          // [12][64][64]
    unsigned short* __restrict__ att)         // [B*3136][384] spatial-major
{
    __shared__ short SM[12 * 2304];           // per-wave V^T [32][72]; reused as Ol[49][392]
    const int tid = threadIdx.x;
    const int lane = tid & 63;
    const int wv = tid >> 6;                  // 0..11 == head
    const int g = lane >> 4, c = lane & 15;
    const int bid = blockIdx.x;
    const int win = (bid & 7) * 256 + (bid >> 3);   // 2048 blocks, XCD-contiguous
    const int head = wv;

    short* Vw = SM + wv * 2304;

    #pragma unroll
    for (int u = 0; u < 8; ++u) {
        int id = u * 64 + lane;
        if (id < 480) {
            int d = id / 15, jj = 49 + id % 15;
            Vw[d * 72 + jj] = 0;
        }
    }

    const unsigned short* qbase = qkw + (size_t)win * 49 * QKV_M + head * HD;

    short8 kf[4], qf[4];
    #pragma unroll
    for (int a = 0; a < 4; ++a) {
        int r = a * 16 + c; if (r > 48) r = 48;
        qf[a] = *(const short8*)(qbase + (size_t)r * QKV_M + g * 8);
        kf[a] = *(const short8*)(qbase + (size_t)r * QKV_M + DIMC + g * 8);
    }

    const unsigned short* vsrc = qbase + 2 * DIMC;
    #pragma unroll
    for (int p = 0; p < 4; ++p) {
        int r = p * 16 + (lane >> 2);
        int chk = (lane & 3) * 8;
        if (r < 49) {
            short8 v8 = *(const short8*)(vsrc + (size_t)r * QKV_M + chk);
            #pragma unroll
            for (int u = 0; u < 8; ++u)
                Vw[(chk + u) * 72 + r] = v8[u];
        }
    }

    f32x4 s[4][4] = {};
    #pragma unroll
    for (int a = 0; a < 4; ++a)
        #pragma unroll
        for (int bi = 0; bi < 4; ++bi)
            s[a][bi] = __builtin_amdgcn_mfma_f32_16x16x32_bf16(kf[a], qf[bi], s[a][bi], 0, 0, 0);

    const float* bp = biasp + head * 4096;
    #pragma unroll
    for (int bi = 0; bi < 4; ++bi) {
        float mx = -1e30f;
        #pragma unroll
        for (int a = 0; a < 4; ++a) {
            #pragma unroll
            for (int e = 0; e < 4; ++e) {
                int j = a * 16 + g * 4 + e;
                float sv = s[a][bi][e] + bp[j * 64 + bi * 16 + c];
                sv = (j < 49) ? sv : -1e30f;
                s[a][bi][e] = sv;
                mx = fmaxf(mx, sv);
            }
        }
        mx = fmaxf(mx, __shfl_xor(mx, 16));
        mx = fmaxf(mx, __shfl_xor(mx, 32));
        float sum = 0.f;
        #pragma unroll
        for (int a = 0; a < 4; ++a) {
            #pragma unroll
            for (int e = 0; e < 4; ++e) {
                int j = a * 16 + g * 4 + e;
                float pv = (j < 49) ? __expf(s[a][bi][e] - mx) : 0.f;
                s[a][bi][e] = pv;
                sum += pv;
            }
        }
        sum += __shfl_xor(sum, 16);
        sum += __shfl_xor(sum, 32);
        float inv = 1.0f / sum;
        #pragma unroll
        for (int a = 0; a < 4; ++a)
            #pragma unroll
            for (int e = 0; e < 4; ++e)
                s[a][bi][e] *= inv;
    }

    unsigned pk[4][4][2];
    #pragma unroll
    for (int a = 0; a < 4; ++a)
        #pragma unroll
        for (int bi = 0; bi < 4; ++bi)
            #pragma unroll
            for (int h = 0; h < 2; ++h)
                pk[a][bi][h] = (unsigned)f2bf(s[a][bi][2 * h]) |
                               ((unsigned)f2bf(s[a][bi][2 * h + 1]) << 16);

    short8 vf[2][2];
    #pragma unroll
    for (int tn = 0; tn < 2; ++tn)
        #pragma unroll
        for (int ks = 0; ks < 2; ++ks)
            vf[tn][ks] = *(const short8*)(&Vw[(tn * 16 + c) * 72 + ks * 32 + g * 8]);

    f32x4 o[4][2] = {};
    const int gsel = g >> 1;
    const int sgb = 2 * (g & 1);
    #pragma unroll
    for (int ks = 0; ks < 2; ++ks) {
        #pragma unroll
        for (int to = 0; to < 4; ++to) {
            union { int w[4]; short8 v; } u;
            #pragma unroll
            for (int w = 0; w < 4; ++w) {
                int srcl = ((sgb + (w >> 1)) * 16 + c) << 2;
                int rA = __builtin_amdgcn_ds_bpermute(srcl, (int)pk[ks * 2 + 0][to][w & 1]);
                int rB = __builtin_amdgcn_ds_bpermute(srcl, (int)pk[ks * 2 + 1][to][w & 1]);
                u.w[w] = gsel ? rB : rA;
            }
            #pragma unroll
            for (int tn = 0; tn < 2; ++tn)
                o[to][tn] = __builtin_amdgcn_mfma_f32_16x16x32_bf16(u.v, vf[tn][ks], o[to][tn], 0, 0, 0);
        }
    }

    // ---- bounce O through LDS (V regions dead after this barrier) ----
    __syncthreads();
    short* Ol = SM;                            // [49][392] shorts (19208 < 27648)
    #pragma unroll
    for (int to = 0; to < 4; ++to) {
        #pragma unroll
        for (int e = 0; e < 4; ++e) {
            int i = to * 16 + g * 4 + e;
            if (i < 49) {
                #pragma unroll
                for (int tn = 0; tn < 2; ++tn)
                    Ol[i * 392 + head * HD + tn * 16 + c] = (short)f2bf(o[to][tn][e]);
            }
        }
    }
    __syncthreads();

    // ---- coalesced store: 49 rows x 48 16-B chunks = 2352 chunks ----
    const int wl = win & 63, bb = win >> 6;
    const size_t obase = (size_t)bb * 3136 * DIMC;
    const int nsp0 = (wl >> 3) * 7 * HWIMG + (wl & 7) * 7;
    #pragma unroll
    for (int p = 0; p < 4; ++p) {
        int ch = p * 768 + tid;
        if (ch < 2352) {
            int row = ch / 48, q = ch - row * 48;
            int nsp = nsp0 + (row / 7) * HWIMG + row % 7;
            short8 v = *(const short8*)(Ol + row * 392 + q * 8);
            *(short8*)(att + obase + (size_t)nsp * DIMC + q * 8) = v;
        }
    }
}

extern "C" void kernel_launch(void* const* d_in, const int* in_sizes, int n_in,
                              void* d_out, int out_size, void* d_ws, size_t ws_size,
                              hipStream_t stream) {
    const float* x          = (const float*)d_in[0];
    const float* w_qkv      = (const float*)d_in[1];
    const float* w_proj     = (const float*)d_in[2];
    const float* b_proj     = (const float*)d_in[3];
    const float* bias_table = (const float*)d_in[4];
    const int*   rel_index  = (const int*)d_in[5];

    // workspace (att aliases xt: xt fully consumed by GEMM1 before att is written)
    unsigned short* xt    = (unsigned short*)d_ws;                   // [NROWS][384]
    unsigned short* att   = xt;                                      // alias, spatial-major
    unsigned short* qkw2  = xt + (size_t)NROWS * KDIM;               // [NROWS][1152]
    unsigned short* wqb   = qkw2 + (size_t)NROWS * QKV_M;            // [1152][384]
    unsigned short* wpb   = wqb + QKV_M * KDIM;                      // [384][384]
    float*          biasp = (float*)(wpb + DIMC * KDIM);             // [12][64][64]

    // q rows (first 384*384 elems) pre-scaled by QSCALE
    cvt_w<<<(QKV_M * KDIM + 255) / 256, 256, 0, stream>>>(w_qkv, wqb, QKV_M * KDIM, DIMC * KDIM);
    cvt_w<<<(DIMC * KDIM + 255) / 256, 256, 0, stream>>>(w_proj, wpb, DIMC * KDIM, 0);
    cvt_x<<<dim3(98, 12, BATCH), 256, 0, stream>>>(x, xt);
    fill_bias<<<192, 256, 0, stream>>>(bias_table, rel_index, biasp);

    // GEMM1: 9 m-tiles x 784 n-tiles = 7056 blocks; coalesced epilogue
    gemm_qkv<<<7056, 256, 0, stream>>>(wqb, xt, qkw2);

    // attention: 2048 blocks (1 window x 12 heads), coalesced O stores
    win_attn<<<2048, 768, 0, stream>>>(qkw2, biasp, att);

    // GEMM2: 3 m-tiles x 784 n-tiles = 2352 blocks
    gemm_proj<<<2352, 256, 0, stream>>>(wpb, att, b_proj, (float*)d_out);
}

// Round 17
// 324.501 us; speedup vs baseline: 1.0773x; 1.0773x over previous
//
#include <hip/hip_runtime.h>

#define NH 12
#define HD 32
#define DIMC 384
#define BATCH 32
#define HWIMG 56
#define NWIN 2048          // 32 batches * 64 windows
#define NROWS 100352       // NWIN * 49, dense window-gathered rows
#define QKV_M 1152
#define KDIM 384
#define QSCALE 0.17677669529663687f

typedef __attribute__((ext_vector_type(8))) short short8;
typedef __attribute__((ext_vector_type(4))) short short4v;
typedef __attribute__((ext_vector_type(4))) float f32x4;

typedef const __attribute__((address_space(1))) unsigned int* gas_ptr;
typedef __attribute__((address_space(3))) unsigned int* las_ptr;

__device__ __forceinline__ unsigned short f2bf(float f) {
    union { float f; unsigned u; } v; v.f = f;
    unsigned r = v.u + 0x7FFF + ((v.u >> 16) & 1);
    return (unsigned short)(r >> 16);
}

// ---------------- fp32 -> bf16 weight convert; first scale_elems get * QSCALE --------
__global__ __launch_bounds__(256) void cvt_w(const float* __restrict__ in,
                                             unsigned short* __restrict__ out,
                                             int n, int scale_elems) {
    int i = blockIdx.x * 256 + threadIdx.x;
    if (i < n) {
        float v = in[i];
        if (i < scale_elems) v *= QSCALE;
        out[i] = f2bf(v);
    }
}

// ---------------- x [B,384,56,56] fp32 -> xt [NROWS,384] bf16 (R13-proven) ----------
__global__ __launch_bounds__(256) void cvt_x(const float* __restrict__ x,
                                             unsigned short* __restrict__ xt) {
    __shared__ float tile[32][33];
    const int b = blockIdx.z, c0 = blockIdx.y * 32, n0 = blockIdx.x * 32;
    const int tid = threadIdx.x;
    const int cl = tid >> 5, nl = tid & 31;
    #pragma unroll
    for (int p = 0; p < 4; ++p)
        tile[cl + p * 8][nl] = x[((size_t)b * DIMC + c0 + cl + p * 8) * 3136 + n0 + nl];
    __syncthreads();
    const int nl2 = tid >> 3, cq = (tid & 7) * 4;
    const int n = n0 + nl2;
    const int nh = n / HWIMG, nw = n % HWIMG;
    const int row = ((b * 64 + (nh / 7) * 8 + nw / 7) * 49 + (nh % 7) * 7 + nw % 7);
    short4v pk;
    #pragma unroll
    for (int u = 0; u < 4; ++u) pk[u] = (short)f2bf(tile[cq + u][nl2]);
    *(short4v*)(xt + (size_t)row * KDIM + c0 + cq) = pk;
}

// ---------------- bias expand: biasp[h][j:64][i:64] fp32, transposed & padded ----------
__global__ __launch_bounds__(256) void fill_bias(const float* __restrict__ bias_table,
                                                 const int* __restrict__ rel_index,
                                                 float* __restrict__ biasp) {
    int id = blockIdx.x * 256 + threadIdx.x;   // 12*4096
    int h = id >> 12, r = id & 4095;
    int j = r >> 6, i = r & 63;
    float v = 0.f;
    if (i < 49 && j < 49) v = bias_table[rel_index[i * 49 + j] * NH + h];
    biasp[id] = v;
}

// ============ GEMM1 (R13-proven): 2-phase 128x128 K-loop + coalesced LDS epilogue =====
__global__ __launch_bounds__(256) void gemm_qkv(
    const unsigned short* __restrict__ A,     // wqb [1152][384] (q rows pre-scaled)
    const unsigned short* __restrict__ Bm,    // xt [NROWS][384]
    unsigned short* __restrict__ qk)          // qkw2 [NROWS][1152]
{
    __shared__ char LBUF[32768];              // K-loop: A|B 16KB each; epilogue: C tile
    char* Al = LBUF;
    char* Bl = LBUF + 16384;
    const int tid = threadIdx.x;

    constexpr int MT = 9;
    const unsigned nwg = gridDim.x;
    const unsigned lin = blockIdx.x;
    const unsigned swz = (lin & 7) * (nwg >> 3) + (lin >> 3);  // XCD-contiguous
    const int m0 = (int)(swz % MT) * 128;
    const int ng0 = (int)(swz / MT) * 128;

    const int lane = tid & 63;
    const int wv = tid >> 6;
    const int wr = wv >> 1, wc = wv & 1;
    const int lrow = lane & 15, kgrp = lane >> 4;

    f32x4 acc[4][4] = {};

    const char* Abase = (const char*)(A + (size_t)m0 * KDIM);
    const char* Bbase = (const char*)(Bm + (size_t)ng0 * KDIM);

    for (int kt = 0; kt < KDIM / 64; ++kt) {
        const int kb = kt * 128;
        #pragma unroll
        for (int it = 0; it < 4; ++it) {
            int chunk = it * 256 + tid;
            int row = chunk >> 3, slot = chunk & 7;
            int scol = (slot ^ (row & 7)) * 16;
            __builtin_amdgcn_global_load_lds(
                (gas_ptr)(Abase + (size_t)row * (KDIM * 2) + kb + scol),
                (las_ptr)(Al + chunk * 16), 16, 0, 0);
        }
        #pragma unroll
        for (int it = 0; it < 4; ++it) {
            int chunk = it * 256 + tid;
            int row = chunk >> 3, slot = chunk & 7;
            int scol = (slot ^ (row & 7)) * 16;
            __builtin_amdgcn_global_load_lds(
                (gas_ptr)(Bbase + (size_t)row * (KDIM * 2) + kb + scol),
                (las_ptr)(Bl + chunk * 16), 16, 0, 0);
        }
        __syncthreads();
        #pragma unroll
        for (int kk = 0; kk < 2; ++kk) {
            short8 af[4], bfr[4];
            #pragma unroll
            for (int i = 0; i < 4; ++i) {
                int row = wr * 64 + i * 16 + lrow;
                int slot = (kk * 4 + kgrp) ^ (row & 7);
                af[i] = *(const short8*)(Al + row * 128 + slot * 16);
            }
            #pragma unroll
            for (int j = 0; j < 4; ++j) {
                int row = wc * 64 + j * 16 + lrow;
                int slot = (kk * 4 + kgrp) ^ (row & 7);
                bfr[j] = *(const short8*)(Bl + row * 128 + slot * 16);
            }
            __builtin_amdgcn_s_setprio(1);
            #pragma unroll
            for (int i = 0; i < 4; ++i)
                #pragma unroll
                for (int j = 0; j < 4; ++j)
                    acc[i][j] = __builtin_amdgcn_mfma_f32_16x16x32_bf16(af[i], bfr[j], acc[i][j], 0, 0, 0);
            __builtin_amdgcn_s_setprio(0);
        }
        __syncthreads();   // all LDS reads done -> safe to repurpose LBUF after loop
    }

    // ---- epilogue: C -> LDS [128 ng][256 B m-slice], XOR-swizzled 16B chunks ----
    #pragma unroll
    for (int i = 0; i < 4; ++i) {
        int mpl = wr * 64 + i * 16 + kgrp * 4;     // local m (covers 4)
        #pragma unroll
        for (int j = 0; j < 4; ++j) {
            int ngl = wc * 64 + j * 16 + lrow;     // local ng
            short4v pk;
            pk.x = (short)f2bf(acc[i][j].x);
            pk.y = (short)f2bf(acc[i][j].y);
            pk.z = (short)f2bf(acc[i][j].z);
            pk.w = (short)f2bf(acc[i][j].w);
            *(short4v*)(LBUF + ngl * 256 + ((mpl * 2) ^ ((ngl & 7) << 4))) = pk;
        }
    }
    __syncthreads();
    // ---- coalesced store: 2048 16-B chunks, 8 per thread ----
    #pragma unroll
    for (int p = 0; p < 8; ++p) {
        int ch = p * 256 + tid;
        int ngl = ch >> 4, q = ch & 15;
        short8 v = *(const short8*)(LBUF + ngl * 256 + ((q * 16) ^ ((ngl & 7) << 4)));
        *(short8*)(qk + (size_t)(ng0 + ngl) * QKV_M + m0 + q * 8) = v;
    }
}

// ---------------- proj GEMM (R4-proven): C = w_proj @ att^T + bias, fp32 NCHW -------
__global__ __launch_bounds__(256) void gemm_proj(
    const unsigned short* __restrict__ A,     // [384][384] bf16
    const unsigned short* __restrict__ Bm,    // att [NROWS][384] spatial-major
    const float* __restrict__ bias,
    float* __restrict__ C)
{
    __shared__ char Al[128 * 128];
    __shared__ char Bl[128 * 128];
    const int tid = threadIdx.x;

    constexpr int MT = 3;
    const unsigned nwg = gridDim.x;
    const unsigned lin = blockIdx.x;
    const unsigned swz = (lin & 7) * (nwg >> 3) + (lin >> 3);
    const int m0 = (int)(swz % MT) * 128;
    const int ng0 = (int)(swz / MT) * 128;

    const int lane = tid & 63;
    const int wv = tid >> 6;
    const int wr = wv >> 1, wc = wv & 1;
    const int lrow = lane & 15, kgrp = lane >> 4;

    f32x4 acc[4][4] = {};

    const char* Abase = (const char*)(A + (size_t)m0 * KDIM);
    const char* Bbase = (const char*)(Bm + (size_t)ng0 * KDIM);

    for (int kt = 0; kt < KDIM / 64; ++kt) {
        const int kb = kt * 128;
        #pragma unroll
        for (int it = 0; it < 4; ++it) {
            int chunk = it * 256 + tid;
            int row = chunk >> 3, slot = chunk & 7;
            int scol = (slot ^ (row & 7)) * 16;
            __builtin_amdgcn_global_load_lds(
                (gas_ptr)(Abase + (size_t)row * (KDIM * 2) + kb + scol),
                (las_ptr)(Al + chunk * 16), 16, 0, 0);
        }
        #pragma unroll
        for (int it = 0; it < 4; ++it) {
            int chunk = it * 256 + tid;
            int row = chunk >> 3, slot = chunk & 7;
            int scol = (slot ^ (row & 7)) * 16;
            __builtin_amdgcn_global_load_lds(
                (gas_ptr)(Bbase + (size_t)row * (KDIM * 2) + kb + scol),
                (las_ptr)(Bl + chunk * 16), 16, 0, 0);
        }
        __syncthreads();
        #pragma unroll
        for (int kk = 0; kk < 2; ++kk) {
            short8 af[4], bfr[4];
            #pragma unroll
            for (int i = 0; i < 4; ++i) {
                int row = wr * 64 + i * 16 + lrow;
                int slot = (kk * 4 + kgrp) ^ (row & 7);
                af[i] = *(const short8*)(Al + row * 128 + slot * 16);
            }
            #pragma unroll
            for (int j = 0; j < 4; ++j) {
                int row = wc * 64 + j * 16 + lrow;
                int slot = (kk * 4 + kgrp) ^ (row & 7);
                bfr[j] = *(const short8*)(Bl + row * 128 + slot * 16);
            }
            __builtin_amdgcn_s_setprio(1);
            #pragma unroll
            for (int i = 0; i < 4; ++i)
                #pragma unroll
                for (int j = 0; j < 4; ++j)
                    acc[i][j] = __builtin_amdgcn_mfma_f32_16x16x32_bf16(af[i], bfr[j], acc[i][j], 0, 0, 0);
            __builtin_amdgcn_s_setprio(0);
        }
        __syncthreads();
    }

    #pragma unroll
    for (int i = 0; i < 4; ++i) {
        int m = m0 + wr * 64 + i * 16 + kgrp * 4;
        float b0 = bias[m + 0], b1 = bias[m + 1], b2 = bias[m + 2], b3 = bias[m + 3];
        #pragma unroll
        for (int j = 0; j < 4; ++j) {
            int ng = ng0 + wc * 64 + j * 16 + lrow;
            unsigned bb = (unsigned)ng / 3136u;
            unsigned nsp = (unsigned)ng - bb * 3136u;
            C[((size_t)bb * DIMC + m + 0) * 3136 + nsp] = acc[i][j].x + b0;
            C[((size_t)bb * DIMC + m + 1) * 3136 + nsp] = acc[i][j].y + b1;
            C[((size_t)bb * DIMC + m + 2) * 3136 + nsp] = acc[i][j].z + b2;
            C[((size_t)bb * DIMC + m + 3) * 3136 + nsp] = acc[i][j].w + b3;
        }
    }
}

// ---------------- MFMA windowed attention (R13-proven, 4 waves x (win,head)) -------
__global__ __launch_bounds__(256) void win_attn(
    const unsigned short* __restrict__ qkw,   // [NROWS][1152], q pre-scaled
    const float* __restrict__ biasp,          // [12][64][64]
    unsigned short* __restrict__ att)         // [B*3136][384] spatial-major
{
    __shared__ short Vl[4][32 * 72];
    const int tid = threadIdx.x;
    const int lane = tid & 63;
    const int wv = tid >> 6;
    const int g = lane >> 4, c = lane & 15;
    const int bid = blockIdx.x;
    const int swz = (bid & 7) * 768 + (bid >> 3);
    const int W = swz * 4 + wv;
    const int win = W / 12;
    const int head = W - win * 12;

    short* Vw = Vl[wv];

    #pragma unroll
    for (int u = 0; u < 8; ++u) {
        int id = u * 64 + lane;
        if (id < 480) {
            int d = id / 15, jj = 49 + id % 15;
            Vw[d * 72 + jj] = 0;
        }
    }

    const unsigned short* qbase = qkw + (size_t)win * 49 * QKV_M + head * HD;

    short8 kf[4], qf[4];
    #pragma unroll
    for (int a = 0; a < 4; ++a) {
        int r = a * 16 + c; if (r > 48) r = 48;
        qf[a] = *(const short8*)(qbase + (size_t)r * QKV_M + g * 8);
        kf[a] = *(const short8*)(qbase + (size_t)r * QKV_M + DIMC + g * 8);
    }

    const unsigned short* vsrc = qbase + 2 * DIMC;
    #pragma unroll
    for (int p = 0; p < 4; ++p) {
        int r = p * 16 + (lane >> 2);
        int chk = (lane & 3) * 8;
        if (r < 49) {
            short8 v8 = *(const short8*)(vsrc + (size_t)r * QKV_M + chk);
            #pragma unroll
            for (int u = 0; u < 8; ++u)
                Vw[(chk + u) * 72 + r] = v8[u];
        }
    }

    f32x4 s[4][4] = {};
    #pragma unroll
    for (int a = 0; a < 4; ++a)
        #pragma unroll
        for (int bi = 0; bi < 4; ++bi)
            s[a][bi] = __builtin_amdgcn_mfma_f32_16x16x32_bf16(kf[a], qf[bi], s[a][bi], 0, 0, 0);

    const float* bp = biasp + head * 4096;
    #pragma unroll
    for (int bi = 0; bi < 4; ++bi) {
        float mx = -1e30f;
        #pragma unroll
        for (int a = 0; a < 4; ++a) {
            #pragma unroll
            for (int e = 0; e < 4; ++e) {
                int j = a * 16 + g * 4 + e;
                float sv = s[a][bi][e] + bp[j * 64 + bi * 16 + c];
                sv = (j < 49) ? sv : -1e30f;
                s[a][bi][e] = sv;
                mx = fmaxf(mx, sv);
            }
        }
        mx = fmaxf(mx, __shfl_xor(mx, 16));
        mx = fmaxf(mx, __shfl_xor(mx, 32));
        float sum = 0.f;
        #pragma unroll
        for (int a = 0; a < 4; ++a) {
            #pragma unroll
            for (int e = 0; e < 4; ++e) {
                int j = a * 16 + g * 4 + e;
                float pv = (j < 49) ? __expf(s[a][bi][e] - mx) : 0.f;
                s[a][bi][e] = pv;
                sum += pv;
            }
        }
        sum += __shfl_xor(sum, 16);
        sum += __shfl_xor(sum, 32);
        float inv = 1.0f / sum;
        #pragma unroll
        for (int a = 0; a < 4; ++a)
            #pragma unroll
            for (int e = 0; e < 4; ++e)
                s[a][bi][e] *= inv;
    }

    unsigned pk[4][4][2];
    #pragma unroll
    for (int a = 0; a < 4; ++a)
        #pragma unroll
        for (int bi = 0; bi < 4; ++bi)
            #pragma unroll
            for (int h = 0; h < 2; ++h)
                pk[a][bi][h] = (unsigned)f2bf(s[a][bi][2 * h]) |
                               ((unsigned)f2bf(s[a][bi][2 * h + 1]) << 16);

    short8 vf[2][2];
    #pragma unroll
    for (int tn = 0; tn < 2; ++tn)
        #pragma unroll
        for (int ks = 0; ks < 2; ++ks)
            vf[tn][ks] = *(const short8*)(&Vw[(tn * 16 + c) * 72 + ks * 32 + g * 8]);

    f32x4 o[4][2] = {};
    const int gsel = g >> 1;
    const int sgb = 2 * (g & 1);
    #pragma unroll
    for (int ks = 0; ks < 2; ++ks) {
        #pragma unroll
        for (int to = 0; to < 4; ++to) {
            union { int w[4]; short8 v; } u;
            #pragma unroll
            for (int w = 0; w < 4; ++w) {
                int srcl = ((sgb + (w >> 1)) * 16 + c) << 2;
                int rA = __builtin_amdgcn_ds_bpermute(srcl, (int)pk[ks * 2 + 0][to][w & 1]);
                int rB = __builtin_amdgcn_ds_bpermute(srcl, (int)pk[ks * 2 + 1][to][w & 1]);
                u.w[w] = gsel ? rB : rA;
            }
            #pragma unroll
            for (int tn = 0; tn < 2; ++tn)
                o[to][tn] = __builtin_amdgcn_mfma_f32_16x16x32_bf16(u.v, vf[tn][ks], o[to][tn], 0, 0, 0);
        }
    }

    const int wl = win & 63, bb = win >> 6;
    const size_t obase = (size_t)bb * 3136 * DIMC;
    const int nsp0 = (wl >> 3) * 7 * HWIMG + (wl & 7) * 7;
    #pragma unroll
    for (int to = 0; to < 4; ++to) {
        #pragma unroll
        for (int e = 0; e < 4; ++e) {
            int i = to * 16 + g * 4 + e;
            if (i < 49) {
                int nsp = nsp0 + (i / 7) * HWIMG + (i % 7);
                unsigned short* ob = att + obase + (size_t)nsp * DIMC + head * HD;
                #pragma unroll
                for (int tn = 0; tn < 2; ++tn)
                    ob[tn * 16 + c] = f2bf(o[to][tn][e]);
            }
        }
    }
}

extern "C" void kernel_launch(void* const* d_in, const int* in_sizes, int n_in,
                              void* d_out, int out_size, void* d_ws, size_t ws_size,
                              hipStream_t stream) {
    const float* x          = (const float*)d_in[0];
    const float* w_qkv      = (const float*)d_in[1];
    const float* w_proj     = (const float*)d_in[2];
    const float* b_proj     = (const float*)d_in[3];
    const float* bias_table = (const float*)d_in[4];
    const int*   rel_index  = (const int*)d_in[5];

    // workspace (att aliases xt: xt fully consumed by GEMM1 before att is written)
    unsigned short* xt    = (unsigned short*)d_ws;                   // [NROWS][384]
    unsigned short* att   = xt;                                      // alias, spatial-major
    unsigned short* qkw2  = xt + (size_t)NROWS * KDIM;               // [NROWS][1152]
    unsigned short* wqb   = qkw2 + (size_t)NROWS * QKV_M;            // [1152][384]
    unsigned short* wpb   = wqb + QKV_M * KDIM;                      // [384][384]
    float*          biasp = (float*)(wpb + DIMC * KDIM);             // [12][64][64]

    // q rows (first 384*384 elems) pre-scaled by QSCALE
    cvt_w<<<(QKV_M * KDIM + 255) / 256, 256, 0, stream>>>(w_qkv, wqb, QKV_M * KDIM, DIMC * KDIM);
    cvt_w<<<(DIMC * KDIM + 255) / 256, 256, 0, stream>>>(w_proj, wpb, DIMC * KDIM, 0);
    cvt_x<<<dim3(98, 12, BATCH), 256, 0, stream>>>(x, xt);
    fill_bias<<<192, 256, 0, stream>>>(bias_table, rel_index, biasp);

    // GEMM1: 9 m-tiles x 784 n-tiles = 7056 blocks; coalesced epilogue
    gemm_qkv<<<7056, 256, 0, stream>>>(wqb, xt, qkw2);

    // attention: 24576 (win,head) waves, 4 per block
    win_attn<<<6144, 256, 0, stream>>>(qkw2, biasp, att);

    // GEMM2: 3 m-tiles x 784 n-tiles = 2352 blocks
    gemm_proj<<<2352, 256, 0, stream>>>(wpb, att, b_proj, (float*)d_out);
}